// Round 4
// baseline (326.731 us; speedup 1.0000x reference)
//
#include <hip/hip_runtime.h>
#include <hip/hip_bf16.h>
#include <stdint.h>

// ---------- types ----------
typedef __bf16  bf16x8 __attribute__((ext_vector_type(8)));
typedef short   s16x8  __attribute__((ext_vector_type(8)));
typedef short   s16x4  __attribute__((ext_vector_type(4)));
typedef int     i32x4  __attribute__((ext_vector_type(4)));
typedef float   f32x4  __attribute__((ext_vector_type(4)));

union Frag { s16x8 s; bf16x8 b; i32x4 i; };

static __device__ __forceinline__ short f2bf(float f) {
    union { float f; unsigned u; } v; v.f = f;
    unsigned r = (v.u + 0x7FFFu + ((v.u >> 16) & 1u)) >> 16;   // RNE
    return (short)r;
}
static __device__ __forceinline__ float bf2f(short s) {
    union { unsigned u; float f; } v; v.u = ((unsigned)(unsigned short)s) << 16;
    return v.f;
}
static __device__ __forceinline__ float fast_rcp(float x) { return __builtin_amdgcn_rcpf(x); }
static __device__ __forceinline__ float sigm(float x) { return fast_rcp(1.0f + __expf(-x)); }
static __device__ __forceinline__ float tanh_fast(float x) {
    float e = __expf(-2.0f * x);
    return (1.0f - e) * fast_rcp(1.0f + e);
}
static __device__ __forceinline__ f32x4 mfma16(bf16x8 a, bf16x8 b, f32x4 c) {
    return __builtin_amdgcn_mfma_f32_16x16x32_bf16(a, b, c, 0, 0, 0);
}

#define GLDS(gp, lp) __builtin_amdgcn_global_load_lds( \
    (const __attribute__((address_space(1))) void*)(gp), \
    (__attribute__((address_space(3))) void*)(lp), 16, 0, 0)

// raw barrier: LDS-ordering only — vm loads/stores stay outstanding (no drain!)
#define BAR_LGKM() asm volatile("s_waitcnt lgkmcnt(0)\n\ts_barrier" ::: "memory")
#define BAR_ALL()  asm volatile("s_waitcnt vmcnt(0) lgkmcnt(0)\n\ts_barrier" ::: "memory")

// Constants
#define TT 128
#define BB 2048
#define HH 64
#define FF 128
#define AA 15
#define YR 32                 // y LDS ring slots (staged 31 steps ahead)
#define LOGITS_OFF 0
#define VF_OFF   3932160
#define HT_OFF   4194304
#define CT_OFF   4325376

// y_sw swizzled: per 16-row tile: 1024 bf16 = [kf(2)][lane(64)][8]
// As B-frag: lane l holds col n=l&15 (batch row), k = 32*kf + 8*(l>>4) + j.

// ============================ encoder ============================
__global__ __launch_bounds__(256) void enc_kernel(
    const float* __restrict__ x, const float* __restrict__ W1, const float* __restrict__ b1,
    const float* __restrict__ W2, const float* __restrict__ b2, short* __restrict__ y_sw)
{
    __shared__ short w1t[64][136];
    __shared__ short w2t[64][72];
    __shared__ short c1buf[4][16][72];
    __shared__ short ybuf[4][16][72];

    const int tid  = threadIdx.x;
    const int lane = tid & 63;
    const int w    = tid >> 6;
    const int c    = lane & 15;
    const int q    = lane >> 4;

    for (int i = tid; i < 128*64; i += 256) { int k = i >> 6, n = i & 63; w1t[n][k] = f2bf(W1[i]); }
    for (int i = tid; i < 64*64;  i += 256) { int k = i >> 6, n = i & 63; w2t[n][k] = f2bf(W2[i]); }

    float b1v[4], b2v[4];
#pragma unroll
    for (int ct = 0; ct < 4; ++ct) { b1v[ct] = b1[16*ct + c]; b2v[ct] = b2[16*ct + c]; }
    __syncthreads();

    for (int it = 0; it < 4; ++it) {
        const int wt = it*4096 + blockIdx.x*4 + w;
        const int r0 = wt * 16;
        Frag af[4];
#pragma unroll
        for (int kf = 0; kf < 4; ++kf) {
            const float* xp = x + (size_t)(r0 + c)*FF + 32*kf + 8*q;
            f32x4 x0 = *(const f32x4*)xp;
            f32x4 x1 = *(const f32x4*)(xp + 4);
#pragma unroll
            for (int jj = 0; jj < 4; ++jj) { af[kf].s[jj] = f2bf(x0[jj]); af[kf].s[4+jj] = f2bf(x1[jj]); }
        }
        f32x4 acc[4];
#pragma unroll
        for (int ct = 0; ct < 4; ++ct) acc[ct] = (f32x4){b1v[ct], b1v[ct], b1v[ct], b1v[ct]};
#pragma unroll
        for (int kf = 0; kf < 4; ++kf)
#pragma unroll
            for (int ct = 0; ct < 4; ++ct) {
                Frag bf; bf.s = *(const s16x8*)&w1t[16*ct + c][32*kf + 8*q];
                acc[ct] = mfma16(af[kf].b, bf.b, acc[ct]);
            }
#pragma unroll
        for (int ct = 0; ct < 4; ++ct)
#pragma unroll
            for (int i = 0; i < 4; ++i)
                c1buf[w][4*q + i][16*ct + c] = f2bf(tanh_fast(acc[ct][i]));
        Frag a2[2];
#pragma unroll
        for (int kf = 0; kf < 2; ++kf) a2[kf].s = *(const s16x8*)&c1buf[w][c][32*kf + 8*q];
        f32x4 acc2[4];
#pragma unroll
        for (int ct = 0; ct < 4; ++ct) acc2[ct] = (f32x4){b2v[ct], b2v[ct], b2v[ct], b2v[ct]};
#pragma unroll
        for (int kf = 0; kf < 2; ++kf)
#pragma unroll
            for (int ct = 0; ct < 4; ++ct) {
                Frag bf; bf.s = *(const s16x8*)&w2t[16*ct + c][32*kf + 8*q];
                acc2[ct] = mfma16(a2[kf].b, bf.b, acc2[ct]);
            }
#pragma unroll
        for (int ct = 0; ct < 4; ++ct)
#pragma unroll
            for (int i = 0; i < 4; ++i)
                ybuf[w][4*q + i][16*ct + c] = f2bf(tanh_fast(acc2[ct][i]));
#pragma unroll
        for (int kf = 0; kf < 2; ++kf) {
            s16x8 yv = *(const s16x8*)&ybuf[w][c][32*kf + 8*q];
            *(s16x8*)(y_sw + (size_t)wt*1024 + kf*512 + lane*8) = yv;
        }
    }
}

// ============================ LSTM scan (transposed gates) ============================
// 128 blocks x 256 thr (4 waves, 1/SIMD). Computes G^T = W @ [y;h]^T per step:
// A = weights (regs), B = state (LDS b128). Lane (q,c): batch row c, h-cols
// 16w+4q..+3 -> h write = 1x ds_write_b64, done-mask = 1 scalar/lane.
// Raw s_barrier with lgkmcnt-only: zero vm drains in the loop.
__global__ __launch_bounds__(256, 1) void scan_kernel(
    const short* __restrict__ y_sw, const float* __restrict__ done,
    const float* __restrict__ h0, const float* __restrict__ c0,
    const float* __restrict__ Wih, const float* __restrict__ bih,
    const float* __restrict__ Whh, const float* __restrict__ bhh,
    const float* __restrict__ Wa, const float* __restrict__ ba,
    const float* __restrict__ Wc, const float* __restrict__ bc,
    float* __restrict__ out_logits, float* __restrict__ out_vf,
    float* __restrict__ hT_out, float* __restrict__ cT_out)
{
    __shared__ short ybig[YR][1024];      // 64 KB   y ring (B-frag order)
    __shared__ short zbuf[2][16][72];     // 4.6 KB  z (unmasked h), [brow][hcol]
    __shared__ float dbuf[TT][16];        // 8 KB    done for all steps
    __shared__ float obuf[2][8][16][16];  // 16 KB   head outs, dbl-buf by 8-chunk

    const int tid  = threadIdx.x;
    const int lane = tid & 63;
    const int w    = tid >> 6;
    const int c    = lane & 15;
    const int q    = lane >> 4;
    const int blk  = blockIdx.x;
    const int b0   = blk * 16;

    // ---- A-frag weights: wfr[a][kf] = W[64a+16w+c][32kf+8q+j] (kf<2: Wih, else Whh)
    Frag  wfr[4][4];
    f32x4 biasv[4];
#pragma unroll
    for (int a = 0; a < 4; ++a) {
        const int gc = 64*a + 16*w + c;
#pragma unroll
        for (int kf = 0; kf < 4; ++kf) {
            const float* wp = (kf < 2) ? (Wih + (size_t)gc*HH + 32*kf + 8*q)
                                       : (Whh + (size_t)gc*HH + 32*(kf-2) + 8*q);
            f32x4 w0 = *(const f32x4*)wp;
            f32x4 w1 = *(const f32x4*)(wp + 4);
#pragma unroll
            for (int jj = 0; jj < 4; ++jj) { wfr[a][kf].s[jj] = f2bf(w0[jj]); wfr[a][kf].s[4+jj] = f2bf(w1[jj]); }
        }
        const int bcol = 64*a + 16*w + 4*q;
        biasv[a] = *(const f32x4*)(bih + bcol);
        f32x4 b2 = *(const f32x4*)(bhh + bcol);
#pragma unroll
        for (int jj = 0; jj < 4; ++jj) biasv[a][jj] += b2[jj];
    }
    // ---- head B-frags: out col c (0..14 Wa, 15 Wc)
    Frag hwf[2];
#pragma unroll
    for (int kf = 0; kf < 2; ++kf)
#pragma unroll
        for (int jj = 0; jj < 8; ++jj) {
            int k = 32*kf + 8*q + jj;
            hwf[kf].s[jj] = f2bf((c < 15) ? Wa[k*AA + c] : Wc[k]);
        }
    const float hbv = (c < 15) ? ba[c] : bc[0];

    // ---- c state: (brow c, hcols 16w+4q+i) — contiguous f32x4
    f32x4 cst = *(const f32x4*)(c0 + (size_t)(b0 + c)*HH + 16*w + 4*q);

    // ---- h0 (unmasked) -> zbuf[1]; mask applied at read with done[0]
    {
        int r = tid & 15, c4 = (tid >> 4) * 4;
        f32x4 hv = *(const f32x4*)(h0 + (size_t)(b0 + r)*HH + c4);
        s16x4 hp;
#pragma unroll
        for (int ii = 0; ii < 4; ++ii) hp[ii] = f2bf(hv[ii]);
        *(s16x4*)&zbuf[1][r][c4] = hp;
    }
    // ---- done -> dbuf (8 GLDS)
#pragma unroll
    for (int i = 0; i < 2; ++i) {
        int j = w*2 + i;
        const float* gp = done + (size_t)(16*j + (lane >> 2))*BB + b0 + 4*(lane & 3);
        GLDS(gp, &dbuf[16*j][0]);
    }
    // ---- y ring prologue: slots 0..30
    for (int s = w; s < 31; s += 4)
#pragma unroll
        for (int half = 0; half < 2; ++half) {
            const short* gp = y_sw + ((size_t)s*128 + blk)*1024 + half*512 + lane*8;
            GLDS(gp, &ybig[s][half*512]);
        }
    BAR_ALL();

    f32x4 hv;   // current h (floats), persists to epilogue

    for (int t = 0; t < TT; ++t) {
        const int rb = (t + 1) & 1, wb = t & 1, slot = t & (YR-1);
        // ---- LDS reads (issue early)
        Frag z0, z1, y0, y1;
        z0.s = *(const s16x8*)&zbuf[rb][c][8*q];
        z1.s = *(const s16x8*)&zbuf[rb][c][32 + 8*q];
        y0.s = *(const s16x8*)&ybig[slot][lane*8];
        y1.s = *(const s16x8*)&ybig[slot][512 + lane*8];
        const float dme = dbuf[t][c];          // broadcast (all q same c)
        // ---- stage y[t+31] into slot (t-1)&31 (read last step; 31-step slack)
        if (w == (t & 3) && t <= TT-32) {
            const int ds = (t + 31) & (YR-1);
#pragma unroll
            for (int half = 0; half < 2; ++half) {
                const short* gp = y_sw + ((size_t)(t+31)*128 + blk)*1024 + half*512 + lane*8;
                GLDS(gp, &ybig[ds][half*512]);
            }
        }
        // ---- head for z[t-1]: reuses z0/z1 (unmasked!), one wave per step
        if (t > 0 && w == (t & 3)) {
            f32x4 ha = (f32x4){hbv, hbv, hbv, hbv};
            ha = mfma16(z0.b, hwf[0].b, ha);
            ha = mfma16(z1.b, hwf[1].b, ha);
            const int tp = t - 1;
#pragma unroll
            for (int i = 0; i < 4; ++i)
                obuf[(tp >> 3) & 1][tp & 7][4*q + i][c] = ha[i];
        }
        // ---- mask h-input with done[t] (bitwise; done is exactly 0.0/1.0)
        const int msk = (dme != 0.0f) ? 0 : -1;
        Frag zm0, zm1;
#pragma unroll
        for (int k = 0; k < 4; ++k) { zm0.i[k] = z0.i[k] & msk; zm1.i[k] = z1.i[k] & msk; }
        // ---- gates: 16 MFMA, A=weights B=state
        f32x4 acc[4];
#pragma unroll
        for (int a = 0; a < 4; ++a) {
            acc[a] = biasv[a];
            acc[a] = mfma16(wfr[a][0].b, y0.b,  acc[a]);
            acc[a] = mfma16(wfr[a][1].b, y1.b,  acc[a]);
            acc[a] = mfma16(wfr[a][2].b, zm0.b, acc[a]);
            acc[a] = mfma16(wfr[a][3].b, zm1.b, acc[a]);
        }
        // ---- elementwise (4 els: brow c, hcols 16w+4q+i), c masked in-reg
#pragma unroll
        for (int i = 0; i < 4; ++i) {
            float cm = (dme != 0.0f) ? 0.0f : cst[i];
            float cn = sigm(acc[1][i])*cm + sigm(acc[0][i])*tanh_fast(acc[2][i]);
            cst[i] = cn;
            hv[i]  = sigm(acc[3][i])*tanh_fast(cn);
        }
        // ---- write z (unmasked h), one b64
        {
            s16x4 hp;
#pragma unroll
            for (int ii = 0; ii < 4; ++ii) hp[ii] = f2bf(hv[ii]);
            *(s16x4*)&zbuf[wb][c][16*w + 4*q] = hp;
        }
        // ---- flush chunk (t>>3)-1 every 8 steps (fire-and-forget stores)
        if ((t & 7) == 1 && t > 8 && lane < 32) {
            const int cc = (t >> 3) - 1;
            const int idx = w*32 + lane;           // 0..127
            const int s = idx >> 4, r = idx & 15;
            const float* ob = &obuf[cc & 1][s][r][0];
            f32x4 o0 = *(const f32x4*)ob,     o1 = *(const f32x4*)(ob+4);
            f32x4 o2 = *(const f32x4*)(ob+8), o3 = *(const f32x4*)(ob+12);
            const size_t row = (size_t)(8*cc + s)*BB + b0 + r;
            float* lp = out_logits + row*AA;
            lp[0]=o0[0]; lp[1]=o0[1]; lp[2]=o0[2]; lp[3]=o0[3];
            lp[4]=o1[0]; lp[5]=o1[1]; lp[6]=o1[2]; lp[7]=o1[3];
            lp[8]=o2[0]; lp[9]=o2[1]; lp[10]=o2[2]; lp[11]=o2[3];
            lp[12]=o3[0]; lp[13]=o3[1]; lp[14]=o3[2];
            out_vf[row] = o3[3];
        }
        BAR_LGKM();   // lgkmcnt(0) + s_barrier — vm ops stay outstanding
    }

    // ---------------- epilogue ----------------
    if (w == 3) {   // head for z[127] (in zbuf[1], barrier-protected)
        Frag z0, z1;
        z0.s = *(const s16x8*)&zbuf[1][c][8*q];
        z1.s = *(const s16x8*)&zbuf[1][c][32 + 8*q];
        f32x4 ha = (f32x4){hbv, hbv, hbv, hbv};
        ha = mfma16(z0.b, hwf[0].b, ha);
        ha = mfma16(z1.b, hwf[1].b, ha);
#pragma unroll
        for (int i = 0; i < 4; ++i) obuf[1][7][4*q + i][c] = ha[i];
    }
    BAR_LGKM();
    if (lane < 32) {   // flush chunk 15 (steps 120..127)
        const int idx = w*32 + lane;
        const int s = idx >> 4, r = idx & 15;
        const float* ob = &obuf[1][s][r][0];
        f32x4 o0 = *(const f32x4*)ob,     o1 = *(const f32x4*)(ob+4);
        f32x4 o2 = *(const f32x4*)(ob+8), o3 = *(const f32x4*)(ob+12);
        const size_t row = (size_t)(120 + s)*BB + b0 + r;
        float* lp = out_logits + row*AA;
        lp[0]=o0[0]; lp[1]=o0[1]; lp[2]=o0[2]; lp[3]=o0[3];
        lp[4]=o1[0]; lp[5]=o1[1]; lp[6]=o1[2]; lp[7]=o1[3];
        lp[8]=o2[0]; lp[9]=o2[1]; lp[10]=o2[2]; lp[11]=o2[3];
        lp[12]=o3[0]; lp[13]=o3[1]; lp[14]=o3[2];
        out_vf[row] = o3[3];
    }
    // hT = z[127] (still in regs), cT = c after step 127 (unmasked)
    *(f32x4*)(hT_out + (size_t)(b0 + c)*HH + 16*w + 4*q) = hv;
    *(f32x4*)(cT_out + (size_t)(b0 + c)*HH + 16*w + 4*q) = cst;
}

// ============================ launch ============================
extern "C" void kernel_launch(void* const* d_in, const int* in_sizes, int n_in,
                              void* d_out, int out_size, void* d_ws, size_t ws_size,
                              hipStream_t stream) {
    const float* x    = (const float*)d_in[0];
    const float* done = (const float*)d_in[1];
    const float* h0   = (const float*)d_in[2];
    const float* c0   = (const float*)d_in[3];
    const float* W1   = (const float*)d_in[4];
    const float* b1   = (const float*)d_in[5];
    const float* W2   = (const float*)d_in[6];
    const float* b2   = (const float*)d_in[7];
    const float* Wih  = (const float*)d_in[8];
    const float* bih  = (const float*)d_in[9];
    const float* Whh  = (const float*)d_in[10];
    const float* bhh  = (const float*)d_in[11];
    const float* Wa   = (const float*)d_in[12];
    const float* ba   = (const float*)d_in[13];
    const float* Wc   = (const float*)d_in[14];
    const float* bc   = (const float*)d_in[15];
    float* out = (float*)d_out;

    short* y_sw = (short*)d_ws;     // 32 MiB swizzled encoder output

    enc_kernel<<<1024, 256, 0, stream>>>(x, W1, b1, W2, b2, y_sw);
    scan_kernel<<<128, 256, 0, stream>>>(y_sw, done, h0, c0, Wih, bih, Whh, bhh,
                                         Wa, ba, Wc, bc,
                                         out + LOGITS_OFF, out + VF_OFF,
                                         out + HT_OFF, out + CT_OFF);
}